// Round 17
// baseline (56.321 us; speedup 1.0000x reference)
//
#include <hip/hip_runtime.h>
#include <hip/hip_bf16.h>

typedef float f32x4 __attribute__((ext_vector_type(4)));
typedef float f32x16 __attribute__((ext_vector_type(16)));
typedef __bf16 bf16x8 __attribute__((ext_vector_type(8)));
typedef unsigned int uint2v __attribute__((ext_vector_type(2)));

#define MFMA16(a, b, c) __builtin_amdgcn_mfma_f32_16x16x32_bf16((a), (b), (c), 0, 0, 0)
#define MFMA32(a, b, c) __builtin_amdgcn_mfma_f32_32x32x16_bf16((a), (b), (c), 0, 0, 0)

static __device__ __forceinline__ short f2s(float f) {
    __hip_bfloat16 h = __float2bfloat16(f);
    return *reinterpret_cast<short*>(&h);
}
static __device__ __forceinline__ unsigned int cvtpk(float lo, float hi) {
    unsigned int r;
    asm("v_cvt_pk_bf16_f32 %0, %1, %2" : "=v"(r) : "v"(lo), "v"(hi));
    return r;
}
static __device__ __forceinline__ float exp2f_fast(float x) {
#if __has_builtin(__builtin_amdgcn_exp2f)
    return __builtin_amdgcn_exp2f(x);
#else
    return exp2f(x);
#endif
}

// ---------------------------------------------------------------------------
// Kernel A (fused front): QKV projection + adj gather, INTERLEAVED block
// mapping (every 7 blocks = 3 QKV + 4 gather) so the compute-bound GEMM and
// memory-bound gather overlap for the whole kernel span, not just the middle.
// Bodies verbatim from verified rounds 11-16.
// ---------------------------------------------------------------------------
__global__ __launch_bounds__(256)
void qkv_and_gather(const float* __restrict__ x,
                    const float* __restrict__ Wq, const float* __restrict__ bq,
                    const float* __restrict__ Wk, const float* __restrict__ bk,
                    const float* __restrict__ Wv, const float* __restrict__ bv,
                    short* __restrict__ Qb, short* __restrict__ Kb, short* __restrict__ Vb,
                    const int* __restrict__ adj, unsigned int* __restrict__ adjG)
{
    __shared__ short As[128 * 72];
    __shared__ short Bs[64 * 72];

    const int bx = blockIdx.x;           // 0..1791 = 256 groups of 7
    const int tid = threadIdx.x;
    const int grp = bx / 7, rem = bx % 7;

    if (rem < 3) {
        // ---------------- QKV GEMM body (verbatim, verified) ----------------
        const int qi = grp * 3 + rem;    // 0..767
        const int lane = tid & 63;
        const int wid = tid >> 6;
        const int wr = wid >> 1, wc = wid & 1;
        const int g = lane >> 4, li = lane & 15;

        const int m0 = (qi & 63) * 128;
        const int gc0 = (qi >> 6) * 64;
        const int mat = gc0 >> 8;
        const float* W    = (mat == 0) ? Wq : (mat == 1) ? Wk : Wv;
        const float* bias = (mat == 0) ? bq : (mat == 1) ? bk : bv;
        short* Out        = (mat == 0) ? Qb : (mat == 1) ? Kb : Vb;
        const int wc0 = gc0 & 255;

        f32x4 acc[4][2] = {};

        const int sr = tid >> 4;
        const int sc4 = (tid & 15) * 4;

        for (int k0 = 0; k0 < 256; k0 += 64) {
            __syncthreads();
#pragma unroll
            for (int it = 0; it < 8; ++it) {
                int row = sr + it * 16;
                float4 v = *reinterpret_cast<const float4*>(&x[(m0 + row) * 256 + k0 + sc4]);
                short4 s4;
                s4.x = f2s(v.x); s4.y = f2s(v.y); s4.z = f2s(v.z); s4.w = f2s(v.w);
                *reinterpret_cast<short4*>(&As[row * 72 + sc4]) = s4;
            }
#pragma unroll
            for (int it = 0; it < 4; ++it) {
                int row = sr + it * 16;
                float4 v = *reinterpret_cast<const float4*>(&W[(wc0 + row) * 256 + k0 + sc4]);
                short4 s4;
                s4.x = f2s(v.x); s4.y = f2s(v.y); s4.z = f2s(v.z); s4.w = f2s(v.w);
                *reinterpret_cast<short4*>(&Bs[row * 72 + sc4]) = s4;
            }
            __syncthreads();
#pragma unroll
            for (int ks = 0; ks < 2; ++ks) {
                const int kb = ks * 32 + g * 8;
                bf16x8 a[4], bfr[2];
#pragma unroll
                for (int i = 0; i < 4; ++i)
                    a[i] = *reinterpret_cast<const bf16x8*>(&As[(wr * 64 + i * 16 + li) * 72 + kb]);
#pragma unroll
                for (int j = 0; j < 2; ++j)
                    bfr[j] = *reinterpret_cast<const bf16x8*>(&Bs[(wc * 32 + j * 16 + li) * 72 + kb]);
#pragma unroll
                for (int i = 0; i < 4; ++i)
#pragma unroll
                    for (int j = 0; j < 2; ++j)
                        acc[i][j] = MFMA16(a[i], bfr[j], acc[i][j]);
            }
        }

#pragma unroll
        for (int j = 0; j < 2; ++j) {
            const int colW = wc0 + wc * 32 + j * 16 + li;
            const int h = colW >> 5, d = colW & 31;
            const float bv_ = bias[colW];
#pragma unroll
            for (int i = 0; i < 4; ++i) {
#pragma unroll
                for (int r = 0; r < 4; ++r) {
                    const int row = m0 + wr * 64 + i * 16 + g * 4 + r;
                    const int bb = row >> 10, nq = row & 1023;
                    Out[((bb * 8 + h) * 1024 + nq) * 32 + d] = f2s(acc[i][j][r] + bv_);
                }
            }
        }
    } else {
        // ---------------- adj gather body (verbatim, verified) ----------------
        const int gx = grp * 4 + (rem - 3);    // 0..1023
        const int qt = gx & 31;
        const int b  = (gx >> 5) & 7;
        const int j0 = (gx >> 8) * 8;

        const int4* base = reinterpret_cast<const int4*>(
            adj + ((size_t)(b * 1024 + qt * 32)) * 1024);
        unsigned int* outT = adjG + ((size_t)(b * 32 + qt)) * 16 * 512;

        const int t = tid >> 4;
        const int i = (tid >> 1) & 7;
        const int laneb = 32 * (tid & 1);

#pragma unroll
        for (int jj = 0; jj < 8; ++jj) {
            const int j = j0 + jj;
            const int4 c = base[j * 256 + tid];
            const unsigned int packed =
                (unsigned)c.x | ((unsigned)c.y << 8) | ((unsigned)c.z << 16) | ((unsigned)c.w << 24);
            outT[t * 512 + i * 64 + (j + laneb)] = packed;
        }
    }
}

// ---------------------------------------------------------------------------
// Kernel B: edge-biased flash attention — verbatim round-16 attn11 (verified
// @~30us: fixed-max softmax, parity chains, V^T granule swizzle, permlane PV).
// ---------------------------------------------------------------------------
__global__ __launch_bounds__(256, 2)
void attn11(const short* __restrict__ Qb, const short* __restrict__ Kb,
            const short* __restrict__ Vb, const unsigned int* __restrict__ adjG,
            const float* __restrict__ edge_emb, short* __restrict__ AO)
{
    __shared__ __align__(16) short Ks[4][64 * 36];   // [tilebuf][row][d]
    __shared__ __align__(16) short Vt[4][32 * 72];   // [tilebuf][d][krow] swizzled
    __shared__ float Etab[8];

    const int tid = threadIdx.x, lane = tid & 63, wid = tid >> 6;
    const int l5 = lane & 31, h32 = lane >> 5;

    // bijective chunked XCD swizzle (512 blocks = 8 XCD x 64)
    const int orig = blockIdx.x + blockIdx.y * 8;
    const int flat = (orig & 7) * 64 + (orig >> 3);
    const int qb = flat & 7, bh = flat >> 3;
    const int b = bh >> 3, h = bh & 7;
    const int qt = qb * 4 + wid;         // wave's q-tile (0..31)
    const int q  = qt * 32 + l5;

    const short* Qh = Qb + bh * (1024 * 32);
    const short* Kh = Kb + bh * (1024 * 32);
    const short* Vh = Vb + bh * (1024 * 32);
    const unsigned int* adjT = adjG + ((size_t)(b * 32 + qt)) * 16 * 512;

    if (tid < 5) Etab[tid] = __expf(edge_emb[tid * 8 + h]);

    // Q fragments (B-operand): col=q=l5, k(d) = c*16 + h32*8 + j
    const bf16x8 qf0 = *reinterpret_cast<const bf16x8*>(&Qh[q * 32 + h32 * 8]);
    const bf16x8 qf1 = *reinterpret_cast<const bf16x8*>(&Qh[q * 32 + 16 + h32 * 8]);

    const float c1 = 0.25503486f;   // log2(e)/sqrt(32)
    const f32x16 zero16 = {};

    f32x16 o[2] = {};
    float lr[2] = { 0.f, 0.f };

    // staging map: thread -> (k-row sr = tid>>2, 16B chunk sc = (tid&3)*8)
    const int sr = tid >> 2;
    const int sc = (tid & 3) * 8;
    const int srh = sr >> 3, srl = sr & 7;     // V-swizzle components
    const int scg2 = (sc >> 3) << 1;

    // prologue: stage tiles 0,1 into buffers 0,1
#pragma unroll
    for (int par = 0; par < 2; ++par) {
        const int row = par * 64 + sr;
        int4 kr = *reinterpret_cast<const int4*>(&Kh[row * 32 + sc]);
        int4 vr = *reinterpret_cast<const int4*>(&Vh[row * 32 + sc]);
        short* kd = &Ks[par][sr * 36 + sc];
        *reinterpret_cast<short4*>(kd)     = *reinterpret_cast<short4*>(&kr);
        *reinterpret_cast<short4*>(kd + 4) = *(reinterpret_cast<short4*>(&kr) + 1);
        const short* vs = reinterpret_cast<const short*>(&vr);
#pragma unroll
        for (int i = 0; i < 8; ++i) {
            const int swz = srh ^ i ^ scg2;
            Vt[par][(sc + i) * 72 + swz * 8 + srl] = vs[i];
        }
    }
    __syncthreads();

    for (int p = 0; p < 8; ++p) {
        const int cur = (p & 1) * 2;

        // ---- adj loads for both tiles of the pair ----
        unsigned int a4[2][8];
#pragma unroll
        for (int par = 0; par < 2; ++par)
#pragma unroll
            for (int i = 0; i < 8; ++i)
                a4[par][i] = adjT[(2 * p + par) * 512 + i * 64 + lane];

        // ---- issue next-pair K/V global loads ----
        int4 kn[2], vn[2];
        if (p < 7) {
#pragma unroll
            for (int par = 0; par < 2; ++par) {
                const int row = (p + 1) * 128 + par * 64 + sr;
                kn[par] = *reinterpret_cast<const int4*>(&Kh[row * 32 + sc]);
                vn[par] = *reinterpret_cast<const int4*>(&Vh[row * 32 + sc]);
            }
        }

        // ---- QK^T both parities (independent) ----
        f32x16 s[2][2];
#pragma unroll
        for (int par = 0; par < 2; ++par)
#pragma unroll
            for (int ks = 0; ks < 2; ++ks) {
                union { short4 h4[2]; bf16x8 v; } kfa, kfb;
                const int rowb = (ks * 32 + l5) * 36;
                const short* KsC = &Ks[cur + par][0];
                kfa.h4[0] = *reinterpret_cast<const short4*>(&KsC[rowb + h32 * 8]);
                kfa.h4[1] = *reinterpret_cast<const short4*>(&KsC[rowb + h32 * 8 + 4]);
                kfb.h4[0] = *reinterpret_cast<const short4*>(&KsC[rowb + 16 + h32 * 8]);
                kfb.h4[1] = *reinterpret_cast<const short4*>(&KsC[rowb + 16 + h32 * 8 + 4]);
                s[par][ks] = MFMA32(kfa.v, qf0, zero16);
                s[par][ks] = MFMA32(kfb.v, qf1, s[par][ks]);
            }

        // ---- fixed-max softmax: p = exp2(s*c1) * E[adj]; pack bf16 ----
        unsigned int pw[2][2][8];
#pragma unroll
        for (int par = 0; par < 2; ++par) {
            float lsum = 0.f;
#pragma unroll
            for (int ks = 0; ks < 2; ++ks) {
#pragma unroll
                for (int rg = 0; rg < 4; ++rg) {
                    const unsigned int aw4 = a4[par][ks * 4 + rg] << 2;
                    float pv[4];
#pragma unroll
                    for (int j = 0; j < 4; ++j) {
                        const float Ev = *reinterpret_cast<const float*>(
                            reinterpret_cast<const char*>(&Etab[0]) +
                            ((aw4 >> (8 * j)) & 0x3FCu));
                        const float pe = exp2f_fast(s[par][ks][rg * 4 + j] * c1);
                        const float pp = pe * Ev;
                        pv[j] = pp;
                        lsum += pp;
                    }
                    pw[par][ks][rg * 2 + 0] = cvtpk(pv[0], pv[1]);
                    pw[par][ks][rg * 2 + 1] = cvtpk(pv[2], pv[3]);
                }
            }
            lr[par] += lsum;     // lane-local; cross-half merge in epilogue
        }

        // ---- per-parity PV (independent chains) ----
#pragma unroll
        for (int par = 0; par < 2; ++par)
#pragma unroll
            for (int kc = 0; kc < 4; ++kc) {
                const int ks = kc >> 1, half = kc & 1;
                const unsigned int A0 = pw[par][ks][4 * half + 0], A1 = pw[par][ks][4 * half + 1];
                const unsigned int B0 = pw[par][ks][4 * half + 2], B1 = pw[par][ks][4 * half + 3];
                union { unsigned int u[4]; bf16x8 v; } P;
#if __has_builtin(__builtin_amdgcn_permlane32_swap)
                uint2v r02 = __builtin_amdgcn_permlane32_swap(A0, B0, false, false);
                uint2v r13 = __builtin_amdgcn_permlane32_swap(A1, B1, false, false);
                P.u[0] = r02.x; P.u[1] = r13.x;
                P.u[2] = r02.y; P.u[3] = r13.y;
#else
                const unsigned int send0 = h32 ? A0 : B0, send1 = h32 ? A1 : B1;
                const unsigned int rv0 = __shfl_xor(send0, 32);
                const unsigned int rv1 = __shfl_xor(send1, 32);
                const unsigned int own0 = h32 ? B0 : A0, own1 = h32 ? B1 : A1;
                P.u[0] = h32 ? rv0 : own0;
                P.u[1] = h32 ? rv1 : own1;
                P.u[2] = h32 ? own0 : rv0;
                P.u[3] = h32 ? own1 : rv1;
#endif
                const int swzr = (kc * 2 + h32) ^ (l5 & 7) ^ ((l5 >> 3) << 1);
                bf16x8 vf = *reinterpret_cast<const bf16x8*>(
                    &Vt[cur + par][l5 * 72 + swzr * 8]);
                o[par] = MFMA32(vf, P.v, o[par]);
            }

        // ---- stage next pair into other buffers; one barrier per pair ----
        if (p < 7) {
#pragma unroll
            for (int par = 0; par < 2; ++par) {
                short* kd = &Ks[(cur ^ 2) + par][sr * 36 + sc];
                *reinterpret_cast<short4*>(kd)     = *reinterpret_cast<short4*>(&kn[par]);
                *reinterpret_cast<short4*>(kd + 4) = *(reinterpret_cast<short4*>(&kn[par]) + 1);
                const short* vs = reinterpret_cast<const short*>(&vn[par]);
#pragma unroll
                for (int i = 0; i < 8; ++i) {
                    const int swz = srh ^ i ^ scg2;
                    Vt[(cur ^ 2) + par][(sc + i) * 72 + swz * 8 + srl] = vs[i];
                }
            }
            __syncthreads();
        }
    }

    // ---- epilogue: merge parities (plain add), one cross-half lsum shfl ----
    float lsum = lr[0] + lr[1];
    lsum += __shfl_xor(lsum, 32);
    const float inv = 1.0f / lsum;
    short* dst = &AO[((size_t)(b * 1024 + q)) * 256 + h * 32];
#pragma unroll
    for (int rg = 0; rg < 4; ++rg) {
        short4 s4;
        s4.x = f2s((o[0][rg * 4 + 0] + o[1][rg * 4 + 0]) * inv);
        s4.y = f2s((o[0][rg * 4 + 1] + o[1][rg * 4 + 1]) * inv);
        s4.z = f2s((o[0][rg * 4 + 2] + o[1][rg * 4 + 2]) * inv);
        s4.w = f2s((o[0][rg * 4 + 3] + o[1][rg * 4 + 3]) * inv);
        *reinterpret_cast<short4*>(&dst[rg * 8 + h32 * 4]) = s4;
    }
}

// ---------------------------------------------------------------------------
// Kernel C: output projection — re-tiled 64x64 (grid 128x4 = 512 blocks,
// 2 blocks/CU vs 1) to halve the exposed serial K-loop latency.  Same
// verified MFMA16 fragment paths; each wave computes a 32x32 output via
// 2x2 frags.
// ---------------------------------------------------------------------------
__global__ __launch_bounds__(256)
void out_gemm64(const short* __restrict__ AO, const float* __restrict__ Wo,
                const float* __restrict__ bo, float* __restrict__ out)
{
    __shared__ short As[64 * 72];
    __shared__ short Bs[64 * 72];

    const int tid = threadIdx.x, lane = tid & 63, wid = tid >> 6;
    const int wr = wid >> 1, wcn = wid & 1;
    const int g = lane >> 4, li = lane & 15;
    const int m0 = blockIdx.x * 64, n0 = blockIdx.y * 64;

    f32x4 acc[2][2] = {};
    const int ar = tid >> 2, ac8 = (tid & 3) * 8;   // A stage: 64 rows x 2 int4
    const int br = tid >> 4, bc4 = (tid & 15) * 4;  // B stage (fp32 source)

    for (int k0 = 0; k0 < 256; k0 += 64) {
        __syncthreads();
        {
            *reinterpret_cast<int4*>(&As[ar * 72 + ac8]) =
                *reinterpret_cast<const int4*>(&AO[(m0 + ar) * 256 + k0 + ac8]);
            *reinterpret_cast<int4*>(&As[ar * 72 + ac8 + 32]) =
                *reinterpret_cast<const int4*>(&AO[(m0 + ar) * 256 + k0 + ac8 + 32]);
        }
#pragma unroll
        for (int it = 0; it < 4; ++it) {
            int row = br + it * 16;
            float4 v = *reinterpret_cast<const float4*>(&Wo[(n0 + row) * 256 + k0 + bc4]);
            short4 s4; s4.x = f2s(v.x); s4.y = f2s(v.y); s4.z = f2s(v.z); s4.w = f2s(v.w);
            *reinterpret_cast<short4*>(&Bs[row * 72 + bc4]) = s4;
        }
        __syncthreads();
#pragma unroll
        for (int ks = 0; ks < 2; ++ks) {
            const int kb = ks * 32 + g * 8;
            bf16x8 a[2], bb[2];
#pragma unroll
            for (int i = 0; i < 2; ++i)
                a[i] = *reinterpret_cast<const bf16x8*>(&As[(wr * 32 + i * 16 + li) * 72 + kb]);
#pragma unroll
            for (int j = 0; j < 2; ++j)
                bb[j] = *reinterpret_cast<const bf16x8*>(&Bs[(wcn * 32 + j * 16 + li) * 72 + kb]);
#pragma unroll
            for (int i = 0; i < 2; ++i)
#pragma unroll
                for (int j = 0; j < 2; ++j)
                    acc[i][j] = MFMA16(a[i], bb[j], acc[i][j]);
        }
    }
#pragma unroll
    for (int j = 0; j < 2; ++j) {
        const int col = n0 + wcn * 32 + j * 16 + li;
        const float bv_ = bo[col];
#pragma unroll
        for (int i = 0; i < 2; ++i)
#pragma unroll
            for (int r = 0; r < 4; ++r) {
                const int row = m0 + wr * 32 + i * 16 + g * 4 + r;
                out[row * 256 + col] = acc[i][j][r] + bv_;
            }
    }
}

extern "C" void kernel_launch(void* const* d_in, const int* in_sizes, int n_in,
                              void* d_out, int out_size, void* d_ws, size_t ws_size,
                              hipStream_t stream)
{
    const float* x  = (const float*)d_in[0];
    const int*   adj = (const int*)d_in[1];
    const float* Wq = (const float*)d_in[2];
    const float* bq = (const float*)d_in[3];
    const float* Wk = (const float*)d_in[4];
    const float* bk = (const float*)d_in[5];
    const float* Wv = (const float*)d_in[6];
    const float* bv = (const float*)d_in[7];
    const float* Wo = (const float*)d_in[8];
    const float* bo = (const float*)d_in[9];
    const float* ee = (const float*)d_in[10];
    float* out = (float*)d_out;

    // Workspace: Qb/Kb/Vb [64][1024][32] bf16 (4MB each), AO [8192][256] bf16 (4MB),
    // adjG [8][32][16][8][64] u32 (8MB)  -> 24MB total (known-good budget)
    short* Qb = (short*)d_ws;
    short* Kb = Qb + 2 * 1024 * 1024;
    short* Vb = Kb + 2 * 1024 * 1024;
    short* AO = Vb + 2 * 1024 * 1024;
    unsigned int* adjG = (unsigned int*)(AO + 2 * 1024 * 1024);

    qkv_and_gather<<<1792, 256, 0, stream>>>(x, Wq, bq, Wk, bk, Wv, bv,
                                             Qb, Kb, Vb, adj, adjG);
    attn11<<<dim3(8, 64), 256, 0, stream>>>(Qb, Kb, Vb, adjG, ee, AO);
    out_gemm64<<<dim3(128, 4), 256, 0, stream>>>(AO, Wo, bo, out);
}

// Round 18
// 52.222 us; speedup vs baseline: 1.0785x; 1.0785x over previous
//
#include <hip/hip_runtime.h>
#include <hip/hip_bf16.h>

typedef float f32x4 __attribute__((ext_vector_type(4)));
typedef float f32x16 __attribute__((ext_vector_type(16)));
typedef __bf16 bf16x8 __attribute__((ext_vector_type(8)));
typedef unsigned int uint2v __attribute__((ext_vector_type(2)));

#define MFMA16(a, b, c) __builtin_amdgcn_mfma_f32_16x16x32_bf16((a), (b), (c), 0, 0, 0)
#define MFMA32(a, b, c) __builtin_amdgcn_mfma_f32_32x32x16_bf16((a), (b), (c), 0, 0, 0)

static __device__ __forceinline__ short f2s(float f) {
    __hip_bfloat16 h = __float2bfloat16(f);
    return *reinterpret_cast<short*>(&h);
}
static __device__ __forceinline__ unsigned int cvtpk(float lo, float hi) {
    unsigned int r;
    asm("v_cvt_pk_bf16_f32 %0, %1, %2" : "=v"(r) : "v"(lo), "v"(hi));
    return r;
}
static __device__ __forceinline__ float exp2f_fast(float x) {
#if __has_builtin(__builtin_amdgcn_exp2f)
    return __builtin_amdgcn_exp2f(x);
#else
    return exp2f(x);
#endif
}

// ---------------------------------------------------------------------------
// Kernel A (fused front): blocks [0,256) = QKV projection with 3-matrix
// A-tile reuse (stage x once per k-step, 3 B-tiles + 3 MFMA sets -> x traffic
// and A-convert VALU / 3); blocks [256,1280) = adj gather (verbatim body).
// ---------------------------------------------------------------------------
__global__ __launch_bounds__(256)
void qkv3_and_gather(const float* __restrict__ x,
                     const float* __restrict__ Wq, const float* __restrict__ bq,
                     const float* __restrict__ Wk, const float* __restrict__ bk,
                     const float* __restrict__ Wv, const float* __restrict__ bv,
                     short* __restrict__ Qb, short* __restrict__ Kb, short* __restrict__ Vb,
                     const int* __restrict__ adj, unsigned int* __restrict__ adjG)
{
    __shared__ short As[128 * 72];
    __shared__ short Bs[3][64 * 72];

    const int bx = blockIdx.x;
    const int tid = threadIdx.x;

    if (bx < 256) {
        // ------------- QKV GEMM, 3 mats per block (A-tile reused) -------------
        const int lane = tid & 63;
        const int wid = tid >> 6;
        const int wr = wid >> 1, wc = wid & 1;
        const int g = lane >> 4, li = lane & 15;

        const int m0 = (bx & 63) * 128;
        const int wc0 = (bx >> 6) * 64;       // weight-row tile (0..255)

        const float* Wm[3]  = { Wq, Wk, Wv };
        const float* bm[3]  = { bq, bk, bv };
        short*       Om[3]  = { Qb, Kb, Vb };

        f32x4 acc[3][4][2] = {};

        const int sr = tid >> 4;
        const int sc4 = (tid & 15) * 4;

        for (int k0 = 0; k0 < 256; k0 += 64) {
            __syncthreads();
#pragma unroll
            for (int it = 0; it < 8; ++it) {
                int row = sr + it * 16;
                float4 v = *reinterpret_cast<const float4*>(&x[(m0 + row) * 256 + k0 + sc4]);
                short4 s4;
                s4.x = f2s(v.x); s4.y = f2s(v.y); s4.z = f2s(v.z); s4.w = f2s(v.w);
                *reinterpret_cast<short4*>(&As[row * 72 + sc4]) = s4;
            }
#pragma unroll
            for (int mat = 0; mat < 3; ++mat) {
#pragma unroll
                for (int it = 0; it < 4; ++it) {
                    int row = sr + it * 16;
                    float4 v = *reinterpret_cast<const float4*>(
                        &Wm[mat][(wc0 + row) * 256 + k0 + sc4]);
                    short4 s4;
                    s4.x = f2s(v.x); s4.y = f2s(v.y); s4.z = f2s(v.z); s4.w = f2s(v.w);
                    *reinterpret_cast<short4*>(&Bs[mat][row * 72 + sc4]) = s4;
                }
            }
            __syncthreads();
#pragma unroll
            for (int ks = 0; ks < 2; ++ks) {
                const int kb = ks * 32 + g * 8;
                bf16x8 a[4];
#pragma unroll
                for (int i = 0; i < 4; ++i)
                    a[i] = *reinterpret_cast<const bf16x8*>(&As[(wr * 64 + i * 16 + li) * 72 + kb]);
#pragma unroll
                for (int mat = 0; mat < 3; ++mat) {
                    bf16x8 bfr[2];
#pragma unroll
                    for (int j = 0; j < 2; ++j)
                        bfr[j] = *reinterpret_cast<const bf16x8*>(
                            &Bs[mat][(wc * 32 + j * 16 + li) * 72 + kb]);
#pragma unroll
                    for (int i = 0; i < 4; ++i)
#pragma unroll
                        for (int j = 0; j < 2; ++j)
                            acc[mat][i][j] = MFMA16(a[i], bfr[j], acc[mat][i][j]);
                }
            }
        }

#pragma unroll
        for (int mat = 0; mat < 3; ++mat) {
#pragma unroll
            for (int j = 0; j < 2; ++j) {
                const int colW = wc0 + wc * 32 + j * 16 + li;
                const int h = colW >> 5, d = colW & 31;
                const float bv_ = bm[mat][colW];
#pragma unroll
                for (int i = 0; i < 4; ++i) {
#pragma unroll
                    for (int r = 0; r < 4; ++r) {
                        const int row = m0 + wr * 64 + i * 16 + g * 4 + r;
                        const int bb = row >> 10, nq = row & 1023;
                        Om[mat][((bb * 8 + h) * 1024 + nq) * 32 + d] =
                            f2s(acc[mat][i][j][r] + bv_);
                    }
                }
            }
        }
    } else {
        // ---------------- adj gather body (verbatim, verified) ----------------
        const int gx = bx - 256;               // 0..1023
        const int qt = gx & 31;
        const int b  = (gx >> 5) & 7;
        const int j0 = (gx >> 8) * 8;

        const int4* base = reinterpret_cast<const int4*>(
            adj + ((size_t)(b * 1024 + qt * 32)) * 1024);
        unsigned int* outT = adjG + ((size_t)(b * 32 + qt)) * 16 * 512;

        const int t = tid >> 4;
        const int i = (tid >> 1) & 7;
        const int laneb = 32 * (tid & 1);

#pragma unroll
        for (int jj = 0; jj < 8; ++jj) {
            const int j = j0 + jj;
            const int4 c = base[j * 256 + tid];
            const unsigned int packed =
                (unsigned)c.x | ((unsigned)c.y << 8) | ((unsigned)c.z << 16) | ((unsigned)c.w << 24);
            outT[t * 512 + i * 64 + (j + laneb)] = packed;
        }
    }
}

// ---------------------------------------------------------------------------
// Kernel B: edge-biased flash attention — verbatim round-16 attn11 (verified
// @~30us: fixed-max softmax, parity chains, V^T granule swizzle, permlane PV).
// ---------------------------------------------------------------------------
__global__ __launch_bounds__(256, 2)
void attn11(const short* __restrict__ Qb, const short* __restrict__ Kb,
            const short* __restrict__ Vb, const unsigned int* __restrict__ adjG,
            const float* __restrict__ edge_emb, short* __restrict__ AO)
{
    __shared__ __align__(16) short Ks[4][64 * 36];   // [tilebuf][row][d]
    __shared__ __align__(16) short Vt[4][32 * 72];   // [tilebuf][d][krow] swizzled
    __shared__ float Etab[8];

    const int tid = threadIdx.x, lane = tid & 63, wid = tid >> 6;
    const int l5 = lane & 31, h32 = lane >> 5;

    // bijective chunked XCD swizzle (512 blocks = 8 XCD x 64)
    const int orig = blockIdx.x + blockIdx.y * 8;
    const int flat = (orig & 7) * 64 + (orig >> 3);
    const int qb = flat & 7, bh = flat >> 3;
    const int b = bh >> 3, h = bh & 7;
    const int qt = qb * 4 + wid;         // wave's q-tile (0..31)
    const int q  = qt * 32 + l5;

    const short* Qh = Qb + bh * (1024 * 32);
    const short* Kh = Kb + bh * (1024 * 32);
    const short* Vh = Vb + bh * (1024 * 32);
    const unsigned int* adjT = adjG + ((size_t)(b * 32 + qt)) * 16 * 512;

    if (tid < 5) Etab[tid] = __expf(edge_emb[tid * 8 + h]);

    // Q fragments (B-operand): col=q=l5, k(d) = c*16 + h32*8 + j
    const bf16x8 qf0 = *reinterpret_cast<const bf16x8*>(&Qh[q * 32 + h32 * 8]);
    const bf16x8 qf1 = *reinterpret_cast<const bf16x8*>(&Qh[q * 32 + 16 + h32 * 8]);

    const float c1 = 0.25503486f;   // log2(e)/sqrt(32)
    const f32x16 zero16 = {};

    f32x16 o[2] = {};
    float lr[2] = { 0.f, 0.f };

    // staging map: thread -> (k-row sr = tid>>2, 16B chunk sc = (tid&3)*8)
    const int sr = tid >> 2;
    const int sc = (tid & 3) * 8;
    const int srh = sr >> 3, srl = sr & 7;     // V-swizzle components
    const int scg2 = (sc >> 3) << 1;

    // prologue: stage tiles 0,1 into buffers 0,1
#pragma unroll
    for (int par = 0; par < 2; ++par) {
        const int row = par * 64 + sr;
        int4 kr = *reinterpret_cast<const int4*>(&Kh[row * 32 + sc]);
        int4 vr = *reinterpret_cast<const int4*>(&Vh[row * 32 + sc]);
        short* kd = &Ks[par][sr * 36 + sc];
        *reinterpret_cast<short4*>(kd)     = *reinterpret_cast<short4*>(&kr);
        *reinterpret_cast<short4*>(kd + 4) = *(reinterpret_cast<short4*>(&kr) + 1);
        const short* vs = reinterpret_cast<const short*>(&vr);
#pragma unroll
        for (int i = 0; i < 8; ++i) {
            const int swz = srh ^ i ^ scg2;
            Vt[par][(sc + i) * 72 + swz * 8 + srl] = vs[i];
        }
    }
    __syncthreads();

    for (int p = 0; p < 8; ++p) {
        const int cur = (p & 1) * 2;

        // ---- adj loads for both tiles of the pair ----
        unsigned int a4[2][8];
#pragma unroll
        for (int par = 0; par < 2; ++par)
#pragma unroll
            for (int i = 0; i < 8; ++i)
                a4[par][i] = adjT[(2 * p + par) * 512 + i * 64 + lane];

        // ---- issue next-pair K/V global loads ----
        int4 kn[2], vn[2];
        if (p < 7) {
#pragma unroll
            for (int par = 0; par < 2; ++par) {
                const int row = (p + 1) * 128 + par * 64 + sr;
                kn[par] = *reinterpret_cast<const int4*>(&Kh[row * 32 + sc]);
                vn[par] = *reinterpret_cast<const int4*>(&Vh[row * 32 + sc]);
            }
        }

        // ---- QK^T both parities (independent) ----
        f32x16 s[2][2];
#pragma unroll
        for (int par = 0; par < 2; ++par)
#pragma unroll
            for (int ks = 0; ks < 2; ++ks) {
                union { short4 h4[2]; bf16x8 v; } kfa, kfb;
                const int rowb = (ks * 32 + l5) * 36;
                const short* KsC = &Ks[cur + par][0];
                kfa.h4[0] = *reinterpret_cast<const short4*>(&KsC[rowb + h32 * 8]);
                kfa.h4[1] = *reinterpret_cast<const short4*>(&KsC[rowb + h32 * 8 + 4]);
                kfb.h4[0] = *reinterpret_cast<const short4*>(&KsC[rowb + 16 + h32 * 8]);
                kfb.h4[1] = *reinterpret_cast<const short4*>(&KsC[rowb + 16 + h32 * 8 + 4]);
                s[par][ks] = MFMA32(kfa.v, qf0, zero16);
                s[par][ks] = MFMA32(kfb.v, qf1, s[par][ks]);
            }

        // ---- fixed-max softmax: p = exp2(s*c1) * E[adj]; pack bf16 ----
        unsigned int pw[2][2][8];
#pragma unroll
        for (int par = 0; par < 2; ++par) {
            float lsum = 0.f;
#pragma unroll
            for (int ks = 0; ks < 2; ++ks) {
#pragma unroll
                for (int rg = 0; rg < 4; ++rg) {
                    const unsigned int aw4 = a4[par][ks * 4 + rg] << 2;
                    float pv[4];
#pragma unroll
                    for (int j = 0; j < 4; ++j) {
                        const float Ev = *reinterpret_cast<const float*>(
                            reinterpret_cast<const char*>(&Etab[0]) +
                            ((aw4 >> (8 * j)) & 0x3FCu));
                        const float pe = exp2f_fast(s[par][ks][rg * 4 + j] * c1);
                        const float pp = pe * Ev;
                        pv[j] = pp;
                        lsum += pp;
                    }
                    pw[par][ks][rg * 2 + 0] = cvtpk(pv[0], pv[1]);
                    pw[par][ks][rg * 2 + 1] = cvtpk(pv[2], pv[3]);
                }
            }
            lr[par] += lsum;     // lane-local; cross-half merge in epilogue
        }

        // ---- per-parity PV (independent chains) ----
#pragma unroll
        for (int par = 0; par < 2; ++par)
#pragma unroll
            for (int kc = 0; kc < 4; ++kc) {
                const int ks = kc >> 1, half = kc & 1;
                const unsigned int A0 = pw[par][ks][4 * half + 0], A1 = pw[par][ks][4 * half + 1];
                const unsigned int B0 = pw[par][ks][4 * half + 2], B1 = pw[par][ks][4 * half + 3];
                union { unsigned int u[4]; bf16x8 v; } P;
#if __has_builtin(__builtin_amdgcn_permlane32_swap)
                uint2v r02 = __builtin_amdgcn_permlane32_swap(A0, B0, false, false);
                uint2v r13 = __builtin_amdgcn_permlane32_swap(A1, B1, false, false);
                P.u[0] = r02.x; P.u[1] = r13.x;
                P.u[2] = r02.y; P.u[3] = r13.y;
#else
                const unsigned int send0 = h32 ? A0 : B0, send1 = h32 ? A1 : B1;
                const unsigned int rv0 = __shfl_xor(send0, 32);
                const unsigned int rv1 = __shfl_xor(send1, 32);
                const unsigned int own0 = h32 ? B0 : A0, own1 = h32 ? B1 : A1;
                P.u[0] = h32 ? rv0 : own0;
                P.u[1] = h32 ? rv1 : own1;
                P.u[2] = h32 ? own0 : rv0;
                P.u[3] = h32 ? own1 : rv1;
#endif
                const int swzr = (kc * 2 + h32) ^ (l5 & 7) ^ ((l5 >> 3) << 1);
                bf16x8 vf = *reinterpret_cast<const bf16x8*>(
                    &Vt[cur + par][l5 * 72 + swzr * 8]);
                o[par] = MFMA32(vf, P.v, o[par]);
            }

        // ---- stage next pair into other buffers; one barrier per pair ----
        if (p < 7) {
#pragma unroll
            for (int par = 0; par < 2; ++par) {
                short* kd = &Ks[(cur ^ 2) + par][sr * 36 + sc];
                *reinterpret_cast<short4*>(kd)     = *reinterpret_cast<short4*>(&kn[par]);
                *reinterpret_cast<short4*>(kd + 4) = *(reinterpret_cast<short4*>(&kn[par]) + 1);
                const short* vs = reinterpret_cast<const short*>(&vn[par]);
#pragma unroll
                for (int i = 0; i < 8; ++i) {
                    const int swz = srh ^ i ^ scg2;
                    Vt[(cur ^ 2) + par][(sc + i) * 72 + swz * 8 + srl] = vs[i];
                }
            }
            __syncthreads();
        }
    }

    // ---- epilogue: merge parities (plain add), one cross-half lsum shfl ----
    float lsum = lr[0] + lr[1];
    lsum += __shfl_xor(lsum, 32);
    const float inv = 1.0f / lsum;
    short* dst = &AO[((size_t)(b * 1024 + q)) * 256 + h * 32];
#pragma unroll
    for (int rg = 0; rg < 4; ++rg) {
        short4 s4;
        s4.x = f2s((o[0][rg * 4 + 0] + o[1][rg * 4 + 0]) * inv);
        s4.y = f2s((o[0][rg * 4 + 1] + o[1][rg * 4 + 1]) * inv);
        s4.z = f2s((o[0][rg * 4 + 2] + o[1][rg * 4 + 2]) * inv);
        s4.w = f2s((o[0][rg * 4 + 3] + o[1][rg * 4 + 3]) * inv);
        *reinterpret_cast<short4*>(&dst[rg * 8 + h32 * 4]) = s4;
    }
}

// ---------------------------------------------------------------------------
// Kernel C: output projection (verbatim round-16 verified version).
// ---------------------------------------------------------------------------
__global__ __launch_bounds__(256)
void out_gemm(const short* __restrict__ AO, const float* __restrict__ Wo,
              const float* __restrict__ bo, float* __restrict__ out)
{
    __shared__ short As[128 * 72];
    __shared__ short Bs[64 * 72];

    const int tid = threadIdx.x, lane = tid & 63, wid = tid >> 6;
    const int wr = wid >> 1, wcn = wid & 1;
    const int g = lane >> 4, li = lane & 15;
    const int m0 = blockIdx.x * 128, n0 = blockIdx.y * 64;

    f32x4 acc[4][2] = {};
    const int ar = tid >> 3, ac8 = (tid & 7) * 8;
    const int br = tid >> 4, bc4 = (tid & 15) * 4;

    for (int k0 = 0; k0 < 256; k0 += 64) {
        __syncthreads();
#pragma unroll
        for (int it = 0; it < 4; ++it) {
            int row = ar + it * 32;
            *reinterpret_cast<int4*>(&As[row * 72 + ac8]) =
                *reinterpret_cast<const int4*>(&AO[(m0 + row) * 256 + k0 + ac8]);
        }
#pragma unroll
        for (int it = 0; it < 4; ++it) {
            int row = br + it * 16;
            float4 v = *reinterpret_cast<const float4*>(&Wo[(n0 + row) * 256 + k0 + bc4]);
            short4 s4; s4.x = f2s(v.x); s4.y = f2s(v.y); s4.z = f2s(v.z); s4.w = f2s(v.w);
            *reinterpret_cast<short4*>(&Bs[row * 72 + bc4]) = s4;
        }
        __syncthreads();
#pragma unroll
        for (int ks = 0; ks < 2; ++ks) {
            const int kb = ks * 32 + g * 8;
            bf16x8 a[4], bb[2];
#pragma unroll
            for (int i = 0; i < 4; ++i)
                a[i] = *reinterpret_cast<const bf16x8*>(&As[(wr * 64 + i * 16 + li) * 72 + kb]);
#pragma unroll
            for (int j = 0; j < 2; ++j)
                bb[j] = *reinterpret_cast<const bf16x8*>(&Bs[(wcn * 32 + j * 16 + li) * 72 + kb]);
#pragma unroll
            for (int i = 0; i < 4; ++i)
#pragma unroll
                for (int j = 0; j < 2; ++j)
                    acc[i][j] = MFMA16(a[i], bb[j], acc[i][j]);
        }
    }
#pragma unroll
    for (int j = 0; j < 2; ++j) {
        const int col = n0 + wcn * 32 + j * 16 + li;
        const float bv_ = bo[col];
#pragma unroll
        for (int i = 0; i < 4; ++i)
#pragma unroll
            for (int r = 0; r < 4; ++r) {
                const int row = m0 + wr * 64 + i * 16 + g * 4 + r;
                out[row * 256 + col] = acc[i][j][r] + bv_;
            }
    }
}

extern "C" void kernel_launch(void* const* d_in, const int* in_sizes, int n_in,
                              void* d_out, int out_size, void* d_ws, size_t ws_size,
                              hipStream_t stream)
{
    const float* x  = (const float*)d_in[0];
    const int*   adj = (const int*)d_in[1];
    const float* Wq = (const float*)d_in[2];
    const float* bq = (const float*)d_in[3];
    const float* Wk = (const float*)d_in[4];
    const float* bk = (const float*)d_in[5];
    const float* Wv = (const float*)d_in[6];
    const float* bv = (const float*)d_in[7];
    const float* Wo = (const float*)d_in[8];
    const float* bo = (const float*)d_in[9];
    const float* ee = (const float*)d_in[10];
    float* out = (float*)d_out;

    // Workspace: Qb/Kb/Vb [64][1024][32] bf16 (4MB each), AO [8192][256] bf16 (4MB),
    // adjG [8][32][16][8][64] u32 (8MB)  -> 24MB total (known-good budget)
    short* Qb = (short*)d_ws;
    short* Kb = Qb + 2 * 1024 * 1024;
    short* Vb = Kb + 2 * 1024 * 1024;
    short* AO = Vb + 2 * 1024 * 1024;
    unsigned int* adjG = (unsigned int*)(AO + 2 * 1024 * 1024);

    qkv3_and_gather<<<1280, 256, 0, stream>>>(x, Wq, bq, Wk, bk, Wv, bv,
                                              Qb, Kb, Vb, adj, adjG);
    attn11<<<dim3(8, 64), 256, 0, stream>>>(Qb, Kb, Vb, adjG, ee, AO);
    out_gemm<<<dim3(64, 4), 256, 0, stream>>>(AO, Wo, bo, out);
}